// Round 1
// baseline (519.181 us; speedup 1.0000x reference)
//
#include <hip/hip_runtime.h>
#include <stdint.h>
#include <math.h>

typedef __bf16 bf16_t;
typedef __attribute__((ext_vector_type(8))) __bf16 bf16x8;
typedef __attribute__((ext_vector_type(4))) __bf16 bf16x4;
typedef __attribute__((ext_vector_type(4))) float f32x4;

#define N_TOK 4096
#define D_MODEL 1024
#define HEADS 16
#define DH 64
#define LOG2E 1.44269504088896340736f

// ---------------- cast x -> bf16 ----------------
__global__ __launch_bounds__(256) void cast_x_kernel(const float* __restrict__ x,
                                                     bf16_t* __restrict__ xb) {
    int i = (blockIdx.x * 256 + threadIdx.x) * 4;
    float4 v = *(const float4*)(x + i);
    bf16x4 o;
    o[0] = (bf16_t)v.x; o[1] = (bf16_t)v.y; o[2] = (bf16_t)v.z; o[3] = (bf16_t)v.w;
    *(bf16x4*)(xb + i) = o;
}

// ---------------- transpose + cast W[k][n] -> Wt[n][k] bf16 ----------------
__global__ __launch_bounds__(256) void transpose_w_kernel(
    const float* __restrict__ W0, const float* __restrict__ W1,
    const float* __restrict__ W2, const float* __restrict__ W3,
    bf16_t* __restrict__ T0, bf16_t* __restrict__ T1,
    bf16_t* __restrict__ T2, bf16_t* __restrict__ T3) {
    __shared__ bf16_t t[64][72];
    const float* W; bf16_t* T;
    switch (blockIdx.z) {
        case 0: W = W0; T = T0; break;
        case 1: W = W1; T = T1; break;
        case 2: W = W2; T = T2; break;
        default: W = W3; T = T3; break;
    }
    int k0 = blockIdx.x * 64, n0 = blockIdx.y * 64;
    int tx = threadIdx.x & 63, ty = threadIdx.x >> 6;
#pragma unroll
    for (int i = 0; i < 16; i++) {
        int kl = ty * 16 + i;
        t[kl][tx] = (bf16_t)W[(size_t)(k0 + kl) * D_MODEL + n0 + tx];
    }
    __syncthreads();
#pragma unroll
    for (int i = 0; i < 16; i++) {
        int nl = ty * 16 + i;
        T[(size_t)(n0 + nl) * D_MODEL + k0 + tx] = t[tx][nl];
    }
}

// ---------------- 128x128 MFMA GEMM: C[M][N] = A[M][K] * Bt[N][K]^T ----------------
template <int WRITE_F32>
__global__ __launch_bounds__(256) void gemm_128(const bf16_t* __restrict__ A,
                                                const bf16_t* __restrict__ Bt,
                                                void* __restrict__ Cout,
                                                int M, int N) {
    constexpr int K = D_MODEL;
    __shared__ __align__(16) bf16_t As[128 * 40];
    __shared__ __align__(16) bf16_t Bs[128 * 40];
    const int tid = threadIdx.x;
    const int m0 = blockIdx.y * 128;
    const int n0 = blockIdx.x * 128;
    const int wave = tid >> 6;
    const int lane = tid & 63;
    const int l15 = lane & 15;
    const int quad = lane >> 4;
    const int wm = (wave >> 1) * 64;
    const int wn = (wave & 1) * 64;
    f32x4 acc[4][4] = {};

    for (int kt = 0; kt < K; kt += 32) {
        __syncthreads();
#pragma unroll
        for (int i = 0; i < 2; i++) {
            int c = tid + 256 * i;       // 512 chunks of 16B per tile
            int row = c >> 2;            // 0..127
            int off = (c & 3) * 8;       // 0,8,16,24
            *(bf16x8*)(&As[row * 40 + off]) =
                *(const bf16x8*)(&A[(size_t)(m0 + row) * K + kt + off]);
            *(bf16x8*)(&Bs[row * 40 + off]) =
                *(const bf16x8*)(&Bt[(size_t)(n0 + row) * K + kt + off]);
        }
        __syncthreads();
        bf16x8 af[4], bfr[4];
#pragma unroll
        for (int mi = 0; mi < 4; mi++)
            af[mi] = *(const bf16x8*)(&As[(wm + mi * 16 + l15) * 40 + quad * 8]);
#pragma unroll
        for (int ni = 0; ni < 4; ni++)
            bfr[ni] = *(const bf16x8*)(&Bs[(wn + ni * 16 + l15) * 40 + quad * 8]);
#pragma unroll
        for (int mi = 0; mi < 4; mi++)
#pragma unroll
            for (int ni = 0; ni < 4; ni++)
                acc[mi][ni] = __builtin_amdgcn_mfma_f32_16x16x32_bf16(
                    af[mi], bfr[ni], acc[mi][ni], 0, 0, 0);
    }
#pragma unroll
    for (int mi = 0; mi < 4; mi++) {
#pragma unroll
        for (int ni = 0; ni < 4; ni++) {
#pragma unroll
            for (int r = 0; r < 4; r++) {
                int row = m0 + wm + mi * 16 + quad * 4 + r;
                int col = n0 + wn + ni * 16 + l15;
                float v = acc[mi][ni][r];
                if (WRITE_F32)
                    ((float*)Cout)[(size_t)row * N + col] = v;
                else
                    ((bf16_t*)Cout)[(size_t)row * N + col] = (bf16_t)v;
            }
        }
    }
}

// ---------------- in-place L2 normalize per 64-elem head-row (Q and K) --------------
__global__ __launch_bounds__(256) void normalize_qk_kernel(bf16_t* __restrict__ Q,
                                                           bf16_t* __restrict__ Kb) {
    int g = blockIdx.x * 16 + (threadIdx.x >> 4);   // 0 .. 131071
    int l16 = threadIdx.x & 15;
    bf16_t* buf = (g < 65536) ? Q : Kb;
    int gg = g & 65535;
    size_t base = (size_t)gg * 64;   // row*1024 + head*64 == gg*64
    bf16x4 v = *(bf16x4*)(buf + base + l16 * 4);
    float f0 = (float)v[0], f1 = (float)v[1], f2 = (float)v[2], f3 = (float)v[3];
    float s = f0 * f0 + f1 * f1 + f2 * f2 + f3 * f3;
    s += __shfl_xor(s, 1, 16);
    s += __shfl_xor(s, 2, 16);
    s += __shfl_xor(s, 4, 16);
    s += __shfl_xor(s, 8, 16);
    float scale = 1.0f / fmaxf(sqrtf(s), 1e-12f);
    v[0] = (bf16_t)(f0 * scale); v[1] = (bf16_t)(f1 * scale);
    v[2] = (bf16_t)(f2 * scale); v[3] = (bf16_t)(f3 * scale);
    *(bf16x4*)(buf + base + l16 * 4) = v;
}

// ---------------- V[n][h*64+d] -> Vt[h][d][n] ----------------
__global__ __launch_bounds__(256) void transpose_v_kernel(const bf16_t* __restrict__ Vb,
                                                          bf16_t* __restrict__ Vt) {
    __shared__ bf16_t t[64][72];
    int n0 = blockIdx.x * 64;
    int h = blockIdx.y;
    int tx = threadIdx.x & 63, ty = threadIdx.x >> 6;
#pragma unroll
    for (int i = 0; i < 16; i++) {
        int nl = ty * 16 + i;
        t[nl][tx] = Vb[(size_t)(n0 + nl) * D_MODEL + h * DH + tx];
    }
    __syncthreads();
#pragma unroll
    for (int i = 0; i < 16; i++) {
        int dl = ty * 16 + i;
        Vt[(size_t)(h * DH + dl) * N_TOK + n0 + tx] = t[tx][dl];
    }
}

// ---------------- flash attention: 1 wave = 16 q rows of one head ----------------
__global__ __launch_bounds__(256) void attn_kernel(const bf16_t* __restrict__ Q,
                                                   const bf16_t* __restrict__ Kb,
                                                   const bf16_t* __restrict__ Vt,
                                                   bf16_t* __restrict__ O) {
    __shared__ __align__(16) bf16_t pt_all[4][16 * 40];
    const int wave = threadIdx.x >> 6;
    const int lane = threadIdx.x & 63;
    const int l15 = lane & 15;
    const int quad = lane >> 4;
    bf16_t* Pt = pt_all[wave];
    const int unit = blockIdx.x * 4 + wave;
    const int h = unit & 15;
    const int i0 = (unit >> 4) * 16;     // same for all 4 waves in a block

    bf16x8 aq[2];
#pragma unroll
    for (int kd = 0; kd < 2; kd++)
        aq[kd] = *(const bf16x8*)(&Q[(size_t)(i0 + l15) * D_MODEL + h * DH + kd * 32 + quad * 8]);

    f32x4 acc[4] = {};
    float m_i[4], l_i[4];
#pragma unroll
    for (int r = 0; r < 4; r++) { m_i[r] = -1e30f; l_i[r] = 0.f; }

    const int jt_max = (i0 + 15) >> 5;   // j-tiles of 32
    for (int jt = 0; jt <= jt_max; jt++) {
        const int j0 = jt * 32;
        f32x4 s0 = {}, s1 = {};
#pragma unroll
        for (int kd = 0; kd < 2; kd++) {
            bf16x8 bk0 = *(const bf16x8*)(&Kb[(size_t)(j0 + l15) * D_MODEL + h * DH + kd * 32 + quad * 8]);
            bf16x8 bk1 = *(const bf16x8*)(&Kb[(size_t)(j0 + 16 + l15) * D_MODEL + h * DH + kd * 32 + quad * 8]);
            s0 = __builtin_amdgcn_mfma_f32_16x16x32_bf16(aq[kd], bk0, s0, 0, 0, 0);
            s1 = __builtin_amdgcn_mfma_f32_16x16x32_bf16(aq[kd], bk1, s1, 0, 0, 0);
        }
        float p0[4], p1[4], alpha[4];
#pragma unroll
        for (int r = 0; r < 4; r++) {
            const int i = i0 + quad * 4 + r;
            float v0 = s0[r] * 8.0f;
            float v1 = s1[r] * 8.0f;
            if (j0 + l15 > i) v0 = -1e30f;
            if (j0 + 16 + l15 > i) v1 = -1e30f;
            float t = fmaxf(v0, v1);
            t = fmaxf(t, __shfl_xor(t, 1, 16));
            t = fmaxf(t, __shfl_xor(t, 2, 16));
            t = fmaxf(t, __shfl_xor(t, 4, 16));
            t = fmaxf(t, __shfl_xor(t, 8, 16));
            float mnew = fmaxf(m_i[r], t);
            alpha[r] = exp2f((m_i[r] - mnew) * LOG2E);
            m_i[r] = mnew;
            p0[r] = exp2f((v0 - mnew) * LOG2E);
            p1[r] = exp2f((v1 - mnew) * LOG2E);
            float ps = p0[r] + p1[r];
            ps += __shfl_xor(ps, 1, 16);
            ps += __shfl_xor(ps, 2, 16);
            ps += __shfl_xor(ps, 4, 16);
            ps += __shfl_xor(ps, 8, 16);
            l_i[r] = l_i[r] * alpha[r] + ps;
        }
#pragma unroll
        for (int ni = 0; ni < 4; ni++) {
            f32x4 a = acc[ni];
            a[0] *= alpha[0]; a[1] *= alpha[1]; a[2] *= alpha[2]; a[3] *= alpha[3];
            acc[ni] = a;
        }
        // P: C-layout -> A-layout via wave-private LDS tile
#pragma unroll
        for (int r = 0; r < 4; r++) {
            Pt[(quad * 4 + r) * 40 + l15] = (bf16_t)p0[r];
            Pt[(quad * 4 + r) * 40 + 16 + l15] = (bf16_t)p1[r];
        }
        __syncthreads();   // all waves same trip count (i0 uniform per block)
        bf16x8 ap = *(const bf16x8*)(&Pt[l15 * 40 + quad * 8]);
#pragma unroll
        for (int ni = 0; ni < 4; ni++) {
            bf16x8 bv = *(const bf16x8*)(&Vt[(size_t)(h * DH + ni * 16 + l15) * N_TOK + j0 + quad * 8]);
            acc[ni] = __builtin_amdgcn_mfma_f32_16x16x32_bf16(ap, bv, acc[ni], 0, 0, 0);
        }
    }
#pragma unroll
    for (int ni = 0; ni < 4; ni++) {
#pragma unroll
        for (int r = 0; r < 4; r++) {
            int i = i0 + quad * 4 + r;
            int col = h * DH + ni * 16 + l15;
            O[(size_t)i * D_MODEL + col] = (bf16_t)(acc[ni][r] / l_i[r]);
        }
    }
}

extern "C" void kernel_launch(void* const* d_in, const int* in_sizes, int n_in,
                              void* d_out, int out_size, void* d_ws, size_t ws_size,
                              hipStream_t stream) {
    const float* x  = (const float*)d_in[0];
    const float* Wq = (const float*)d_in[1];
    const float* Wk = (const float*)d_in[2];
    const float* Wv = (const float*)d_in[3];
    const float* Wo = (const float*)d_in[4];
    float* out = (float*)d_out;
    char* ws = (char*)d_ws;
    const size_t MB = 1024 * 1024;
    bf16_t* xb  = (bf16_t*)(ws);             // 8 MB
    bf16_t* Wqt = (bf16_t*)(ws + 8 * MB);    // 2 MB each
    bf16_t* Wkt = (bf16_t*)(ws + 10 * MB);
    bf16_t* Wvt = (bf16_t*)(ws + 12 * MB);
    bf16_t* Wot = (bf16_t*)(ws + 14 * MB);
    bf16_t* Qb  = (bf16_t*)(ws + 16 * MB);   // 8 MB each
    bf16_t* Kb  = (bf16_t*)(ws + 24 * MB);
    bf16_t* Vb  = (bf16_t*)(ws + 32 * MB);
    bf16_t* Vt  = (bf16_t*)(ws + 40 * MB);
    bf16_t* Ob  = (bf16_t*)(ws + 48 * MB);   // ends at 56 MB

    cast_x_kernel<<<4096, 256, 0, stream>>>(x, xb);
    dim3 gw(16, 16, 4);
    transpose_w_kernel<<<gw, 256, 0, stream>>>(Wq, Wk, Wv, Wo, Wqt, Wkt, Wvt, Wot);
    dim3 gg(D_MODEL / 128, N_TOK / 128);
    gemm_128<0><<<gg, 256, 0, stream>>>(xb, Wqt, Qb, N_TOK, D_MODEL);
    gemm_128<0><<<gg, 256, 0, stream>>>(xb, Wkt, Kb, N_TOK, D_MODEL);
    gemm_128<0><<<gg, 256, 0, stream>>>(xb, Wvt, Vb, N_TOK, D_MODEL);
    normalize_qk_kernel<<<8192, 256, 0, stream>>>(Qb, Kb);
    dim3 gv(N_TOK / 64, HEADS);
    transpose_v_kernel<<<gv, 256, 0, stream>>>(Vb, Vt);
    attn_kernel<<<1024, 256, 0, stream>>>(Qb, Kb, Vt, Ob);
    gemm_128<1><<<gg, 256, 0, stream>>>(Ob, Wot, out, N_TOK, D_MODEL);
}

// Round 2
// 290.584 us; speedup vs baseline: 1.7867x; 1.7867x over previous
//
#include <hip/hip_runtime.h>
#include <stdint.h>
#include <math.h>

typedef __bf16 bf16_t;
typedef __attribute__((ext_vector_type(8))) __bf16 bf16x8;
typedef __attribute__((ext_vector_type(4))) __bf16 bf16x4;
typedef __attribute__((ext_vector_type(4))) float f32x4;

#define N_TOK 4096
#define D_MODEL 1024
#define HEADS 16
#define DH 64
// p = exp(8*dot - 8.125) = exp2(dot*C1 - C2); constant shift cancels in softmax.
#define C1 11.541560327111707f   // 8 * log2(e)
#define C2 11.721897207207671f   // 8.125 * log2(e)

// async global->LDS 16B copy (dest = wave-uniform base + lane*16)
__device__ __forceinline__ void async_copy16(const void* g, void* l) {
    __builtin_amdgcn_global_load_lds(
        (const __attribute__((address_space(1))) unsigned int*)g,
        (__attribute__((address_space(3))) unsigned int*)l, 16, 0, 0);
}

// ---------------- cast x -> bf16 ----------------
__global__ __launch_bounds__(256) void cast_x_kernel(const float* __restrict__ x,
                                                     bf16_t* __restrict__ xb) {
    int i = (blockIdx.x * 256 + threadIdx.x) * 4;
    float4 v = *(const float4*)(x + i);
    bf16x4 o;
    o[0] = (bf16_t)v.x; o[1] = (bf16_t)v.y; o[2] = (bf16_t)v.z; o[3] = (bf16_t)v.w;
    *(bf16x4*)(xb + i) = o;
}

// ---------------- transpose + cast W[k][n] -> Wt[n][k] bf16 ----------------
__global__ __launch_bounds__(256) void transpose_w_kernel(
    const float* __restrict__ W0, const float* __restrict__ W1,
    const float* __restrict__ W2, const float* __restrict__ W3,
    bf16_t* __restrict__ T0, bf16_t* __restrict__ T1,
    bf16_t* __restrict__ T2, bf16_t* __restrict__ T3) {
    __shared__ bf16_t t[64][72];
    const float* W; bf16_t* T;
    switch (blockIdx.z) {
        case 0: W = W0; T = T0; break;
        case 1: W = W1; T = T1; break;
        case 2: W = W2; T = T2; break;
        default: W = W3; T = T3; break;
    }
    int k0 = blockIdx.x * 64, n0 = blockIdx.y * 64;
    int tx = threadIdx.x & 63, ty = threadIdx.x >> 6;
#pragma unroll
    for (int i = 0; i < 16; i++) {
        int kl = ty * 16 + i;
        t[kl][tx] = (bf16_t)W[(size_t)(k0 + kl) * D_MODEL + n0 + tx];
    }
    __syncthreads();
#pragma unroll
    for (int i = 0; i < 16; i++) {
        int nl = ty * 16 + i;
        T[(size_t)(n0 + nl) * D_MODEL + k0 + tx] = t[tx][nl];
    }
}

// ------- 128x128 MFMA GEMM, m97-style global_load_lds staging, 8 waves -------
// C[M][N] = A[M][K] * Bt[N][K]^T
template <int WRITE_F32>
__global__ __launch_bounds__(512) void gemm_128(const bf16_t* __restrict__ A,
                                                const bf16_t* __restrict__ Bt,
                                                void* __restrict__ Cout,
                                                int M, int N) {
    constexpr int K = D_MODEL;
    __shared__ __align__(16) bf16_t As[128 * 32];   // unpadded: global_load_lds dest
    __shared__ __align__(16) bf16_t Bs[128 * 32];
    const int tid = threadIdx.x;
    const int m0 = blockIdx.y * 128;
    const int n0 = blockIdx.x * 128;
    const int wave = tid >> 6;
    const int lane = tid & 63;
    const int l15 = lane & 15;
    const int quad = lane >> 4;
    const int wm = (wave >> 1) * 32;   // 4 row-strips of 32
    const int wn = (wave & 1) * 64;    // 2 col-strips of 64
    f32x4 acc[2][4] = {};

    // staging: chunk c = tid (0..511) -> row = c>>2, koff = (c&3)*8 elems
    const int srow = tid >> 2;
    const int soff = (tid & 3) * 8;
    const bf16_t* ga = A + (size_t)(m0 + srow) * K + soff;
    const bf16_t* gb = Bt + (size_t)(n0 + srow) * K + soff;
    bf16_t* lA = &As[tid * 8];
    bf16_t* lB = &Bs[tid * 8];

    for (int kt = 0; kt < K; kt += 32) {
        __syncthreads();                 // prior frag reads done before overwrite
        async_copy16(ga, lA);
        async_copy16(gb, lB);
        ga += 32; gb += 32;
        __syncthreads();                 // drains vmcnt -> LDS tiles ready
        bf16x8 af[2], bfr[4];
#pragma unroll
        for (int mi = 0; mi < 2; mi++)
            af[mi] = *(const bf16x8*)(&As[(wm + mi * 16 + l15) * 32 + quad * 8]);
#pragma unroll
        for (int ni = 0; ni < 4; ni++)
            bfr[ni] = *(const bf16x8*)(&Bs[(wn + ni * 16 + l15) * 32 + quad * 8]);
#pragma unroll
        for (int mi = 0; mi < 2; mi++)
#pragma unroll
            for (int ni = 0; ni < 4; ni++)
                acc[mi][ni] = __builtin_amdgcn_mfma_f32_16x16x32_bf16(
                    af[mi], bfr[ni], acc[mi][ni], 0, 0, 0);
    }
#pragma unroll
    for (int mi = 0; mi < 2; mi++) {
#pragma unroll
        for (int ni = 0; ni < 4; ni++) {
#pragma unroll
            for (int r = 0; r < 4; r++) {
                int row = m0 + wm + mi * 16 + quad * 4 + r;
                int col = n0 + wn + ni * 16 + l15;
                float v = acc[mi][ni][r];
                if (WRITE_F32)
                    ((float*)Cout)[(size_t)row * N + col] = v;
                else
                    ((bf16_t*)Cout)[(size_t)row * N + col] = (bf16_t)v;
            }
        }
    }
}

// ---------------- in-place L2 normalize per 64-elem head-row (Q and K) --------------
__global__ __launch_bounds__(256) void normalize_qk_kernel(bf16_t* __restrict__ Q,
                                                           bf16_t* __restrict__ Kb) {
    int g = blockIdx.x * 16 + (threadIdx.x >> 4);   // 0 .. 131071
    int l16 = threadIdx.x & 15;
    bf16_t* buf = (g < 65536) ? Q : Kb;
    int gg = g & 65535;
    size_t base = (size_t)gg * 64;
    bf16x4 v = *(bf16x4*)(buf + base + l16 * 4);
    float f0 = (float)v[0], f1 = (float)v[1], f2 = (float)v[2], f3 = (float)v[3];
    float s = f0 * f0 + f1 * f1 + f2 * f2 + f3 * f3;
    s += __shfl_xor(s, 1, 16);
    s += __shfl_xor(s, 2, 16);
    s += __shfl_xor(s, 4, 16);
    s += __shfl_xor(s, 8, 16);
    float scale = 1.0f / fmaxf(sqrtf(s), 1e-12f);
    v[0] = (bf16_t)(f0 * scale); v[1] = (bf16_t)(f1 * scale);
    v[2] = (bf16_t)(f2 * scale); v[3] = (bf16_t)(f3 * scale);
    *(bf16x4*)(buf + base + l16 * 4) = v;
}

// ---------------- V[n][h*64+d] -> Vt[h][d][n] ----------------
__global__ __launch_bounds__(256) void transpose_v_kernel(const bf16_t* __restrict__ Vb,
                                                          bf16_t* __restrict__ Vt) {
    __shared__ bf16_t t[64][72];
    int n0 = blockIdx.x * 64;
    int h = blockIdx.y;
    int tx = threadIdx.x & 63, ty = threadIdx.x >> 6;
#pragma unroll
    for (int i = 0; i < 16; i++) {
        int nl = ty * 16 + i;
        t[nl][tx] = Vb[(size_t)(n0 + nl) * D_MODEL + h * DH + tx];
    }
    __syncthreads();
#pragma unroll
    for (int i = 0; i < 16; i++) {
        int dl = ty * 16 + i;
        Vt[(size_t)(h * DH + dl) * N_TOK + n0 + tx] = t[tx][dl];
    }
}

// ---------------- flash attention, fixed-max softmax ----------------
// block = 1 head x 64 consecutive q-rows (4 waves x 16 rows), shared K/V staging.
// XCD-swizzled head mapping, heaviest row-groups first.
__global__ __launch_bounds__(256) void attn_kernel(const bf16_t* __restrict__ Q,
                                                   const bf16_t* __restrict__ Kb,
                                                   const bf16_t* __restrict__ Vt,
                                                   bf16_t* __restrict__ O) {
    __shared__ __align__(16) bf16_t Ks[32 * 64];       // [j 32][d 64] unpadded
    __shared__ __align__(16) bf16_t Vs[64 * 32];       // [d 64][j 32] unpadded
    __shared__ __align__(16) bf16_t Pt[4][16 * 40];    // wave-private P tile

    const int tid = threadIdx.x;
    const int wave = tid >> 6;
    const int lane = tid & 63;
    const int l15 = lane & 15;
    const int quad = lane >> 4;

    const int xcd = blockIdx.x & 7;
    const int idx = blockIdx.x >> 3;          // 0..127
    const int h = xcd * 2 + (idx & 1);        // 2 heads per XCD for L2 locality
    const int rg = 63 - (idx >> 1);           // heaviest row-groups first
    const int i0 = rg * 64 + wave * 16;
    const int jt_blk = rg * 2 + 1;            // block's last j-tile
    const int jt_w = (i0 + 15) >> 5;          // this wave's last (masked) j-tile

    bf16x8 aq[2];
#pragma unroll
    for (int kd = 0; kd < 2; kd++)
        aq[kd] = *(const bf16x8*)(&Q[(size_t)(i0 + l15) * D_MODEL + h * DH + kd * 32 + quad * 8]);

    f32x4 acc[4] = {};
    float l_part[4] = {0.f, 0.f, 0.f, 0.f};

    // staging addresses: K chunk = (j=tid>>3, off=(tid&7)*8); V chunk = (d=tid>>2, off=(tid&3)*8)
    const bf16_t* gK = Kb + (size_t)(tid >> 3) * D_MODEL + h * DH + (tid & 7) * 8;
    const bf16_t* gV = Vt + (size_t)(h * DH + (tid >> 2)) * N_TOK + (tid & 3) * 8;
    bf16_t* lK = &Ks[tid * 8];
    bf16_t* lV = &Vs[tid * 8];
    bf16_t* P = Pt[wave];

    for (int jt = 0; jt <= jt_blk; jt++) {
        __syncthreads();                       // prior tile's LDS reads done
        async_copy16(gK + (size_t)jt * 32 * D_MODEL, lK);
        async_copy16(gV + jt * 32, lV);
        __syncthreads();                       // vmcnt drained: tiles ready
        if (jt > jt_w) continue;               // wave-uniform skip (still hits barriers)

        f32x4 s0 = {}, s1 = {};
#pragma unroll
        for (int kd = 0; kd < 2; kd++) {
            bf16x8 bk0 = *(const bf16x8*)(&Ks[(l15) * 64 + kd * 32 + quad * 8]);
            bf16x8 bk1 = *(const bf16x8*)(&Ks[(16 + l15) * 64 + kd * 32 + quad * 8]);
            s0 = __builtin_amdgcn_mfma_f32_16x16x32_bf16(aq[kd], bk0, s0, 0, 0, 0);
            s1 = __builtin_amdgcn_mfma_f32_16x16x32_bf16(aq[kd], bk1, s1, 0, 0, 0);
        }
        const int j0 = jt * 32;
        float p0[4], p1[4];
        if (jt == jt_w) {                      // diagonal tile: mask j > i
#pragma unroll
            for (int r = 0; r < 4; r++) {
                const int i = i0 + quad * 4 + r;
                p0[r] = (j0 + l15 > i) ? 0.f : __builtin_amdgcn_exp2f(s0[r] * C1 - C2);
                p1[r] = (j0 + 16 + l15 > i) ? 0.f : __builtin_amdgcn_exp2f(s1[r] * C1 - C2);
                l_part[r] += p0[r] + p1[r];
            }
        } else {                               // interior: no mask
#pragma unroll
            for (int r = 0; r < 4; r++) {
                p0[r] = __builtin_amdgcn_exp2f(s0[r] * C1 - C2);
                p1[r] = __builtin_amdgcn_exp2f(s1[r] * C1 - C2);
                l_part[r] += p0[r] + p1[r];
            }
        }
        // P: C-layout -> A-layout via wave-private LDS (in-order DS ops, no barrier)
#pragma unroll
        for (int r = 0; r < 4; r++) {
            P[(quad * 4 + r) * 40 + l15] = (bf16_t)p0[r];
            P[(quad * 4 + r) * 40 + 16 + l15] = (bf16_t)p1[r];
        }
        bf16x8 ap = *(const bf16x8*)(&P[l15 * 40 + quad * 8]);
#pragma unroll
        for (int ni = 0; ni < 4; ni++) {
            bf16x8 bv = *(const bf16x8*)(&Vs[(ni * 16 + l15) * 32 + quad * 8]);
            acc[ni] = __builtin_amdgcn_mfma_f32_16x16x32_bf16(ap, bv, acc[ni], 0, 0, 0);
        }
    }

    float inv[4];
#pragma unroll
    for (int r = 0; r < 4; r++) {
        float l = l_part[r];
        l += __shfl_xor(l, 1, 16);
        l += __shfl_xor(l, 2, 16);
        l += __shfl_xor(l, 4, 16);
        l += __shfl_xor(l, 8, 16);
        inv[r] = 1.0f / l;
    }
#pragma unroll
    for (int ni = 0; ni < 4; ni++)
#pragma unroll
        for (int r = 0; r < 4; r++) {
            int i = i0 + quad * 4 + r;
            int col = h * DH + ni * 16 + l15;
            O[(size_t)i * D_MODEL + col] = (bf16_t)(acc[ni][r] * inv[r]);
        }
}

extern "C" void kernel_launch(void* const* d_in, const int* in_sizes, int n_in,
                              void* d_out, int out_size, void* d_ws, size_t ws_size,
                              hipStream_t stream) {
    const float* x  = (const float*)d_in[0];
    const float* Wq = (const float*)d_in[1];
    const float* Wk = (const float*)d_in[2];
    const float* Wv = (const float*)d_in[3];
    const float* Wo = (const float*)d_in[4];
    float* out = (float*)d_out;
    char* ws = (char*)d_ws;
    const size_t MB = 1024 * 1024;
    bf16_t* xb  = (bf16_t*)(ws);             // 8 MB
    bf16_t* Wqt = (bf16_t*)(ws + 8 * MB);    // 2 MB each
    bf16_t* Wkt = (bf16_t*)(ws + 10 * MB);
    bf16_t* Wvt = (bf16_t*)(ws + 12 * MB);
    bf16_t* Wot = (bf16_t*)(ws + 14 * MB);
    bf16_t* Qb  = (bf16_t*)(ws + 16 * MB);   // 8 MB each
    bf16_t* Kb  = (bf16_t*)(ws + 24 * MB);
    bf16_t* Vb  = (bf16_t*)(ws + 32 * MB);
    bf16_t* Vt  = (bf16_t*)(ws + 40 * MB);
    bf16_t* Ob  = (bf16_t*)(ws + 48 * MB);   // ends at 56 MB

    cast_x_kernel<<<4096, 256, 0, stream>>>(x, xb);
    dim3 gw(16, 16, 4);
    transpose_w_kernel<<<gw, 256, 0, stream>>>(Wq, Wk, Wv, Wo, Wqt, Wkt, Wvt, Wot);
    dim3 gg(D_MODEL / 128, N_TOK / 128);
    gemm_128<0><<<gg, 512, 0, stream>>>(xb, Wqt, Qb, N_TOK, D_MODEL);
    gemm_128<0><<<gg, 512, 0, stream>>>(xb, Wkt, Kb, N_TOK, D_MODEL);
    gemm_128<0><<<gg, 512, 0, stream>>>(xb, Wvt, Vb, N_TOK, D_MODEL);
    normalize_qk_kernel<<<8192, 256, 0, stream>>>(Qb, Kb);
    dim3 gv(N_TOK / 64, HEADS);
    transpose_v_kernel<<<gv, 256, 0, stream>>>(Vb, Vt);
    attn_kernel<<<1024, 256, 0, stream>>>(Qb, Kb, Vt, Ob);
    gemm_128<1><<<gg, 512, 0, stream>>>(Ob, Wot, out, N_TOK, D_MODEL);
}

// Round 3
// 282.567 us; speedup vs baseline: 1.8374x; 1.0284x over previous
//
#include <hip/hip_runtime.h>
#include <stdint.h>
#include <math.h>

typedef __bf16 bf16_t;
typedef __attribute__((ext_vector_type(8))) __bf16 bf16x8;
typedef __attribute__((ext_vector_type(4))) __bf16 bf16x4;
typedef __attribute__((ext_vector_type(4))) float f32x4;

#define N_TOK 4096
#define D_MODEL 1024
#define HEADS 16
#define DH 64
// p = exp(8*dot - 8.125) = exp2(dot*C1 - C2); constant shift cancels in softmax.
#define C1 11.541560327111707f   // 8 * log2(e)
#define C2 11.721897207207671f   // 8.125 * log2(e)

// async global->LDS 16B copy (dest = wave-uniform base + lane*16)
__device__ __forceinline__ void async_copy16(const void* g, void* l) {
    __builtin_amdgcn_global_load_lds(
        (const __attribute__((address_space(1))) unsigned int*)g,
        (__attribute__((address_space(3))) unsigned int*)l, 16, 0, 0);
}

// ---------------- cast x -> bf16 ----------------
__global__ __launch_bounds__(256) void cast_x_kernel(const float* __restrict__ x,
                                                     bf16_t* __restrict__ xb) {
    int i = (blockIdx.x * 256 + threadIdx.x) * 4;
    float4 v = *(const float4*)(x + i);
    bf16x4 o;
    o[0] = (bf16_t)v.x; o[1] = (bf16_t)v.y; o[2] = (bf16_t)v.z; o[3] = (bf16_t)v.w;
    *(bf16x4*)(xb + i) = o;
}

// ------- transpose + cast W[k][n] -> Wt[n][k] bf16 (q,k,v into one 3072-row buf) ----
__global__ __launch_bounds__(256) void transpose_w_kernel(
    const float* __restrict__ W0, const float* __restrict__ W1,
    const float* __restrict__ W2, const float* __restrict__ W3,
    bf16_t* __restrict__ T0, bf16_t* __restrict__ T1,
    bf16_t* __restrict__ T2, bf16_t* __restrict__ T3) {
    __shared__ bf16_t t[64][72];
    const float* W; bf16_t* T;
    switch (blockIdx.z) {
        case 0: W = W0; T = T0; break;
        case 1: W = W1; T = T1; break;
        case 2: W = W2; T = T2; break;
        default: W = W3; T = T3; break;
    }
    int k0 = blockIdx.x * 64, n0 = blockIdx.y * 64;
    int tx = threadIdx.x & 63, ty = threadIdx.x >> 6;
#pragma unroll
    for (int i = 0; i < 16; i++) {
        int kl = ty * 16 + i;
        t[kl][tx] = (bf16_t)W[(size_t)(k0 + kl) * D_MODEL + n0 + tx];
    }
    __syncthreads();
#pragma unroll
    for (int i = 0; i < 16; i++) {
        int nl = ty * 16 + i;
        T[(size_t)(n0 + nl) * D_MODEL + k0 + tx] = t[tx][nl];
    }
}

// ------- 128x128 MFMA GEMM, swizzled global_load_lds staging, 4 waves x (64x64) -----
// C[M][ldc] tile = A[M][1024] * Bt[N][1024]^T ; optional fused L2-norm per 64-col head
template <int WRITE_F32, int NORM>
__global__ __launch_bounds__(256) void gemm_tile(const bf16_t* __restrict__ A,
                                                 const bf16_t* __restrict__ Bt,
                                                 void* __restrict__ Cout, int ldc) {
    constexpr int K = D_MODEL;
    __shared__ __align__(16) bf16_t As[128 * 32];
    __shared__ __align__(16) bf16_t Bs[128 * 32];
    const int tid = threadIdx.x;
    const int m0 = blockIdx.y * 128;
    const int n0 = blockIdx.x * 128;
    const int wave = tid >> 6;
    const int lane = tid & 63;
    const int l15 = lane & 15;
    const int quad = lane >> 4;
    const int wm = (wave >> 1) * 64;
    const int wn = (wave & 1) * 64;
    const int fsw = quad ^ ((l15 >> 1) & 3);      // read-side swizzled chunk
    f32x4 acc[4][4] = {};

    // staging: thread t handles LDS chunks t and t+256; chunk L: row=L>>2, store-chunk L&3
    const int srow = tid >> 2;
    const int cg = (tid & 3) ^ ((srow >> 1) & 3); // global chunk (same for row+64)
    const bf16_t* gA = A + (size_t)(m0 + srow) * K + cg * 8;
    const bf16_t* gB = Bt + (size_t)(n0 + srow) * K + cg * 8;
    bf16_t* lA = &As[tid * 8];
    bf16_t* lB = &Bs[tid * 8];
    constexpr int HGAP = 64 * K;

    for (int kt = 0; kt < K; kt += 32) {
        __syncthreads();
        async_copy16(gA + kt, lA);
        async_copy16(gA + HGAP + kt, lA + 2048);
        async_copy16(gB + kt, lB);
        async_copy16(gB + HGAP + kt, lB + 2048);
        __syncthreads();
        bf16x8 af[4], bfr[4];
#pragma unroll
        for (int mi = 0; mi < 4; mi++)
            af[mi] = *(const bf16x8*)(&As[(wm + mi * 16 + l15) * 32 + fsw * 8]);
#pragma unroll
        for (int ni = 0; ni < 4; ni++)
            bfr[ni] = *(const bf16x8*)(&Bs[(wn + ni * 16 + l15) * 32 + fsw * 8]);
#pragma unroll
        for (int mi = 0; mi < 4; mi++)
#pragma unroll
            for (int ni = 0; ni < 4; ni++)
                acc[mi][ni] = __builtin_amdgcn_mfma_f32_16x16x32_bf16(
                    af[mi], bfr[ni], acc[mi][ni], 0, 0, 0);
    }

    if (NORM && n0 < 2048) {   // wave's 64-col span == one head: fused F.normalize
#pragma unroll
        for (int mi = 0; mi < 4; mi++)
#pragma unroll
            for (int r = 0; r < 4; r++) {
                float s = 0.f;
#pragma unroll
                for (int ni = 0; ni < 4; ni++) {
                    float v = acc[mi][ni][r];
                    s += v * v;
                }
                s += __shfl_xor(s, 1);
                s += __shfl_xor(s, 2);
                s += __shfl_xor(s, 4);
                s += __shfl_xor(s, 8);
                float sc = 1.0f / fmaxf(sqrtf(s), 1e-12f);
#pragma unroll
                for (int ni = 0; ni < 4; ni++) acc[mi][ni][r] *= sc;
            }
    }
#pragma unroll
    for (int mi = 0; mi < 4; mi++)
#pragma unroll
        for (int ni = 0; ni < 4; ni++)
#pragma unroll
            for (int r = 0; r < 4; r++) {
                int row = m0 + wm + mi * 16 + quad * 4 + r;
                int col = n0 + wn + ni * 16 + l15;
                float v = acc[mi][ni][r];
                if (WRITE_F32)
                    ((float*)Cout)[(size_t)row * ldc + col] = v;
                else
                    ((bf16_t*)Cout)[(size_t)row * ldc + col] = (bf16_t)v;
            }
}

// ---------------- V (QKV cols 2048..3071) -> Vt[h][d][n] ----------------
__global__ __launch_bounds__(256) void transpose_v_kernel(const bf16_t* __restrict__ QKV,
                                                          bf16_t* __restrict__ Vt) {
    __shared__ bf16_t t[64][72];
    int n0 = blockIdx.x * 64;
    int h = blockIdx.y;
    int tx = threadIdx.x & 63, ty = threadIdx.x >> 6;
#pragma unroll
    for (int i = 0; i < 16; i++) {
        int nl = ty * 16 + i;
        t[nl][tx] = QKV[(size_t)(n0 + nl) * 3072 + 2048 + h * DH + tx];
    }
    __syncthreads();
#pragma unroll
    for (int i = 0; i < 16; i++) {
        int dl = ty * 16 + i;
        Vt[(size_t)(h * DH + dl) * N_TOK + n0 + tx] = t[tx][dl];
    }
}

// ---------------- flash attention, fixed-max softmax ----------------
// block = 2 waves x 32 q-rows of one head; swizzled dbuf K/V staging, 1 barrier/tile.
__global__ __launch_bounds__(128) void attn_kernel(const bf16_t* __restrict__ QKV,
                                                   const bf16_t* __restrict__ Vt,
                                                   bf16_t* __restrict__ O) {
    __shared__ __align__(16) bf16_t Ks[2][2048];   // [buf][32 j x 64 d] swizzled
    __shared__ __align__(16) bf16_t Vs[2][2048];   // [buf][64 d x 32 j] swizzled
    __shared__ __align__(16) bf16_t Pt[2][32 * 40];
    const int tid = threadIdx.x;
    const int wave = tid >> 6;
    const int lane = tid & 63;
    const int l15 = lane & 15;
    const int quad = lane >> 4;
    const int fsw = quad ^ ((l15 >> 1) & 3);

    const int xcd = blockIdx.x & 7;
    const int idx = blockIdx.x >> 3;
    const int h = xcd * 2 + (idx & 1);       // 2 heads per XCD
    const int rg = 63 - (idx >> 1);          // heaviest row-groups first
    const int i0 = rg * 64 + wave * 32;
    const int jt_blk = rg * 2 + 1;
    const int jt_w = rg * 2 + wave;

    bf16x8 aq[2][2];
#pragma unroll
    for (int s_ = 0; s_ < 2; s_++)
#pragma unroll
        for (int kd = 0; kd < 2; kd++)
            aq[s_][kd] = *(const bf16x8*)(&QKV[(size_t)(i0 + s_ * 16 + l15) * 3072 +
                                               h * DH + kd * 32 + quad * 8]);

    f32x4 acc[2][4] = {};
    float l_part[2][4] = {};

    // staging: K chunk L: row=L>>3, c=(L&7)^(row&7); V chunk L: d=L>>2, c=(L&3)^((d>>1)&3)
    const int krow = tid >> 3;
    const int kc = (tid & 7) ^ (krow & 7);
    const bf16_t* gK = QKV + (size_t)krow * 3072 + 1024 + h * DH + kc * 8;
    const int vd = tid >> 2;
    const int vc = (tid & 3) ^ ((vd >> 1) & 3);
    const bf16_t* gV = Vt + (size_t)(h * DH + vd) * N_TOK + vc * 8;
    bf16_t* P = Pt[wave];

    {   // preload tile 0 into buf 0
        async_copy16(gK, &Ks[0][tid * 8]);
        async_copy16(gK + 16 * 3072, &Ks[0][tid * 8 + 1024]);
        async_copy16(gV, &Vs[0][tid * 8]);
        async_copy16(gV + 32 * N_TOK, &Vs[0][tid * 8 + 1024]);
    }

    for (int jt = 0; jt <= jt_blk; jt++) {
        __syncthreads();                        // buf[jt&1] ready; prior reads retired
        if (jt < jt_blk) {                      // prefetch next tile into other buf
            const int b = (jt + 1) & 1;
            const bf16_t* gKn = gK + (size_t)(jt + 1) * 32 * 3072;
            const bf16_t* gVn = gV + (jt + 1) * 32;
            async_copy16(gKn, &Ks[b][tid * 8]);
            async_copy16(gKn + 16 * 3072, &Ks[b][tid * 8 + 1024]);
            async_copy16(gVn, &Vs[b][tid * 8]);
            async_copy16(gVn + 32 * N_TOK, &Vs[b][tid * 8 + 1024]);
        }
        if (jt > jt_w) continue;                // wave-uniform; still hits barriers
        const int b = jt & 1;
        const bf16_t* KS = Ks[b];
        const bf16_t* VS = Vs[b];

        bf16x8 bk[2][2];
#pragma unroll
        for (int kd = 0; kd < 2; kd++)
#pragma unroll
            for (int jh = 0; jh < 2; jh++)
                bk[kd][jh] = *(const bf16x8*)(&KS[(jh * 16 + l15) * 64 +
                                                  (((kd * 4 + quad) ^ (l15 & 7)) * 8)]);
        f32x4 sS[2][2] = {};
#pragma unroll
        for (int s_ = 0; s_ < 2; s_++)
#pragma unroll
            for (int kd = 0; kd < 2; kd++) {
                sS[s_][0] = __builtin_amdgcn_mfma_f32_16x16x32_bf16(aq[s_][kd], bk[kd][0], sS[s_][0], 0, 0, 0);
                sS[s_][1] = __builtin_amdgcn_mfma_f32_16x16x32_bf16(aq[s_][kd], bk[kd][1], sS[s_][1], 0, 0, 0);
            }
        const int j0 = jt * 32;
        if (jt == jt_w) {                       // diagonal tile: causal mask
#pragma unroll
            for (int s_ = 0; s_ < 2; s_++)
#pragma unroll
                for (int r = 0; r < 4; r++) {
                    const int i = i0 + s_ * 16 + quad * 4 + r;
                    float p0 = (j0 + l15 > i) ? 0.f : __builtin_amdgcn_exp2f(sS[s_][0][r] * C1 - C2);
                    float p1 = (j0 + 16 + l15 > i) ? 0.f : __builtin_amdgcn_exp2f(sS[s_][1][r] * C1 - C2);
                    l_part[s_][r] += p0 + p1;
                    P[(s_ * 16 + quad * 4 + r) * 40 + l15] = (bf16_t)p0;
                    P[(s_ * 16 + quad * 4 + r) * 40 + 16 + l15] = (bf16_t)p1;
                }
        } else {
#pragma unroll
            for (int s_ = 0; s_ < 2; s_++)
#pragma unroll
                for (int r = 0; r < 4; r++) {
                    float p0 = __builtin_amdgcn_exp2f(sS[s_][0][r] * C1 - C2);
                    float p1 = __builtin_amdgcn_exp2f(sS[s_][1][r] * C1 - C2);
                    l_part[s_][r] += p0 + p1;
                    P[(s_ * 16 + quad * 4 + r) * 40 + l15] = (bf16_t)p0;
                    P[(s_ * 16 + quad * 4 + r) * 40 + 16 + l15] = (bf16_t)p1;
                }
        }
        bf16x8 bv[4];
#pragma unroll
        for (int ni = 0; ni < 4; ni++)
            bv[ni] = *(const bf16x8*)(&VS[(ni * 16 + l15) * 32 + fsw * 8]);
#pragma unroll
        for (int s_ = 0; s_ < 2; s_++) {
            bf16x8 ap = *(const bf16x8*)(&P[(s_ * 16 + l15) * 40 + quad * 8]);
#pragma unroll
            for (int ni = 0; ni < 4; ni++)
                acc[s_][ni] = __builtin_amdgcn_mfma_f32_16x16x32_bf16(ap, bv[ni], acc[s_][ni], 0, 0, 0);
        }
    }

    float inv[2][4];
#pragma unroll
    for (int s_ = 0; s_ < 2; s_++)
#pragma unroll
        for (int r = 0; r < 4; r++) {
            float l = l_part[s_][r];
            l += __shfl_xor(l, 1);
            l += __shfl_xor(l, 2);
            l += __shfl_xor(l, 4);
            l += __shfl_xor(l, 8);
            inv[s_][r] = 1.0f / l;
        }
#pragma unroll
    for (int s_ = 0; s_ < 2; s_++)
#pragma unroll
        for (int ni = 0; ni < 4; ni++)
#pragma unroll
            for (int r = 0; r < 4; r++) {
                int i = i0 + s_ * 16 + quad * 4 + r;
                int col = h * DH + ni * 16 + l15;
                O[(size_t)i * D_MODEL + col] = (bf16_t)(acc[s_][ni][r] * inv[s_][r]);
            }
}

extern "C" void kernel_launch(void* const* d_in, const int* in_sizes, int n_in,
                              void* d_out, int out_size, void* d_ws, size_t ws_size,
                              hipStream_t stream) {
    const float* x  = (const float*)d_in[0];
    const float* Wq = (const float*)d_in[1];
    const float* Wk = (const float*)d_in[2];
    const float* Wv = (const float*)d_in[3];
    const float* Wo = (const float*)d_in[4];
    float* out = (float*)d_out;
    char* ws = (char*)d_ws;
    const size_t MB = 1024 * 1024;
    bf16_t* xb   = (bf16_t*)(ws);             // 8 MB
    bf16_t* Wt3  = (bf16_t*)(ws + 8 * MB);    // 6 MB  [3072][1024] q|k|v
    bf16_t* Wot  = (bf16_t*)(ws + 14 * MB);   // 2 MB
    bf16_t* QKV  = (bf16_t*)(ws + 16 * MB);   // 24 MB [4096][3072]
    bf16_t* Vt   = (bf16_t*)(ws + 40 * MB);   // 8 MB  [16][64][4096]
    bf16_t* Ob   = (bf16_t*)(ws + 48 * MB);   // 8 MB  -> ends at 56 MB

    cast_x_kernel<<<4096, 256, 0, stream>>>(x, xb);
    dim3 gw(16, 16, 4);
    transpose_w_kernel<<<gw, 256, 0, stream>>>(Wq, Wk, Wv, Wo,
                                               Wt3, Wt3 + 1024 * 1024, Wt3 + 2 * 1024 * 1024, Wot);
    dim3 gqkv(3072 / 128, N_TOK / 128);
    gemm_tile<0, 1><<<gqkv, 256, 0, stream>>>(xb, Wt3, QKV, 3072);
    dim3 gv(N_TOK / 64, HEADS);
    transpose_v_kernel<<<gv, 256, 0, stream>>>(QKV, Vt);
    attn_kernel<<<1024, 128, 0, stream>>>(QKV, Vt, Ob);
    dim3 go(D_MODEL / 128, N_TOK / 128);
    gemm_tile<1, 0><<<go, 256, 0, stream>>>(Ob, Wot, out, D_MODEL);
}

// Round 4
// 273.747 us; speedup vs baseline: 1.8966x; 1.0322x over previous
//
#include <hip/hip_runtime.h>
#include <stdint.h>
#include <math.h>

typedef __bf16 bf16_t;
typedef __attribute__((ext_vector_type(8))) __bf16 bf16x8;
typedef __attribute__((ext_vector_type(4))) __bf16 bf16x4;
typedef __attribute__((ext_vector_type(4))) float f32x4;

#define N_TOK 4096
#define D_MODEL 1024
#define HEADS 16
#define DH 64
// p = exp(8*dot - 8.125) = exp2(dot*C1 - C2); constant shift cancels in softmax.
#define C1 11.541560327111707f   // 8 * log2(e)
#define C2 11.721897207207671f   // 8.125 * log2(e)

// async global->LDS 16B copy (dest = wave-uniform base + lane*16)
__device__ __forceinline__ void async_copy16(const void* g, void* l) {
    __builtin_amdgcn_global_load_lds(
        (const __attribute__((address_space(1))) unsigned int*)g,
        (__attribute__((address_space(3))) unsigned int*)l, 16, 0, 0);
}

// ---------------- cast x -> bf16 ----------------
__global__ __launch_bounds__(256) void cast_x_kernel(const float* __restrict__ x,
                                                     bf16_t* __restrict__ xb) {
    int i = (blockIdx.x * 256 + threadIdx.x) * 4;
    float4 v = *(const float4*)(x + i);
    bf16x4 o;
    o[0] = (bf16_t)v.x; o[1] = (bf16_t)v.y; o[2] = (bf16_t)v.z; o[3] = (bf16_t)v.w;
    *(bf16x4*)(xb + i) = o;
}

// ------- transpose + cast W[k][n] -> Wt[n][k] bf16 (q,k,v into one 3072-row buf) ----
__global__ __launch_bounds__(256) void transpose_w_kernel(
    const float* __restrict__ W0, const float* __restrict__ W1,
    const float* __restrict__ W2, const float* __restrict__ W3,
    bf16_t* __restrict__ T0, bf16_t* __restrict__ T1,
    bf16_t* __restrict__ T2, bf16_t* __restrict__ T3) {
    __shared__ bf16_t t[64][72];
    const float* W; bf16_t* T;
    switch (blockIdx.z) {
        case 0: W = W0; T = T0; break;
        case 1: W = W1; T = T1; break;
        case 2: W = W2; T = T2; break;
        default: W = W3; T = T3; break;
    }
    int k0 = blockIdx.x * 64, n0 = blockIdx.y * 64;
    int tx = threadIdx.x & 63, ty = threadIdx.x >> 6;
#pragma unroll
    for (int i = 0; i < 16; i++) {
        int kl = ty * 16 + i;
        t[kl][tx] = (bf16_t)W[(size_t)(k0 + kl) * D_MODEL + n0 + tx];
    }
    __syncthreads();
#pragma unroll
    for (int i = 0; i < 16; i++) {
        int nl = ty * 16 + i;
        T[(size_t)(n0 + nl) * D_MODEL + k0 + tx] = t[tx][nl];
    }
}

// ------- 128x128 MFMA GEMM, swizzled global_load_lds staging, 4 waves x (64x64) -----
// C[M][ldc] tile = A[M][1024] * Bt[N][1024]^T ; optional fused L2-norm per 64-col head
template <int WRITE_F32, int NORM>
__global__ __launch_bounds__(256) void gemm_tile(const bf16_t* __restrict__ A,
                                                 const bf16_t* __restrict__ Bt,
                                                 void* __restrict__ Cout, int ldc) {
    constexpr int K = D_MODEL;
    __shared__ __align__(16) bf16_t As[128 * 32];
    __shared__ __align__(16) bf16_t Bs[128 * 32];
    const int tid = threadIdx.x;
    const int m0 = blockIdx.y * 128;
    const int n0 = blockIdx.x * 128;
    const int wave = tid >> 6;
    const int lane = tid & 63;
    const int l15 = lane & 15;
    const int quad = lane >> 4;
    const int wm = (wave >> 1) * 64;
    const int wn = (wave & 1) * 64;
    const int fsw = quad ^ ((l15 >> 1) & 3);      // read-side swizzled chunk
    f32x4 acc[4][4] = {};

    // staging: thread t handles LDS chunks t and t+256; chunk L: row=L>>2, store-chunk L&3
    const int srow = tid >> 2;
    const int cg = (tid & 3) ^ ((srow >> 1) & 3); // global chunk (same for row+64)
    const bf16_t* gA = A + (size_t)(m0 + srow) * K + cg * 8;
    const bf16_t* gB = Bt + (size_t)(n0 + srow) * K + cg * 8;
    bf16_t* lA = &As[tid * 8];
    bf16_t* lB = &Bs[tid * 8];
    constexpr int HGAP = 64 * K;

    for (int kt = 0; kt < K; kt += 32) {
        __syncthreads();
        async_copy16(gA + kt, lA);
        async_copy16(gA + HGAP + kt, lA + 2048);
        async_copy16(gB + kt, lB);
        async_copy16(gB + HGAP + kt, lB + 2048);
        __syncthreads();
        bf16x8 af[4], bfr[4];
#pragma unroll
        for (int mi = 0; mi < 4; mi++)
            af[mi] = *(const bf16x8*)(&As[(wm + mi * 16 + l15) * 32 + fsw * 8]);
#pragma unroll
        for (int ni = 0; ni < 4; ni++)
            bfr[ni] = *(const bf16x8*)(&Bs[(wn + ni * 16 + l15) * 32 + fsw * 8]);
#pragma unroll
        for (int mi = 0; mi < 4; mi++)
#pragma unroll
            for (int ni = 0; ni < 4; ni++)
                acc[mi][ni] = __builtin_amdgcn_mfma_f32_16x16x32_bf16(
                    af[mi], bfr[ni], acc[mi][ni], 0, 0, 0);
    }

    if (NORM && n0 < 2048) {   // wave's 64-col span == one head: fused F.normalize
#pragma unroll
        for (int mi = 0; mi < 4; mi++)
#pragma unroll
            for (int r = 0; r < 4; r++) {
                float s = 0.f;
#pragma unroll
                for (int ni = 0; ni < 4; ni++) {
                    float v = acc[mi][ni][r];
                    s += v * v;
                }
                s += __shfl_xor(s, 1);
                s += __shfl_xor(s, 2);
                s += __shfl_xor(s, 4);
                s += __shfl_xor(s, 8);
                float sc = 1.0f / fmaxf(sqrtf(s), 1e-12f);
#pragma unroll
                for (int ni = 0; ni < 4; ni++) acc[mi][ni][r] *= sc;
            }
    }
#pragma unroll
    for (int mi = 0; mi < 4; mi++)
#pragma unroll
        for (int ni = 0; ni < 4; ni++)
#pragma unroll
            for (int r = 0; r < 4; r++) {
                int row = m0 + wm + mi * 16 + quad * 4 + r;
                int col = n0 + wn + ni * 16 + l15;
                float v = acc[mi][ni][r];
                if (WRITE_F32)
                    ((float*)Cout)[(size_t)row * ldc + col] = v;
                else
                    ((bf16_t*)Cout)[(size_t)row * ldc + col] = (bf16_t)v;
            }
}

// ---------------- V (QKV cols 2048..3071) -> Vt[h][d][n] ----------------
__global__ __launch_bounds__(256) void transpose_v_kernel(const bf16_t* __restrict__ QKV,
                                                          bf16_t* __restrict__ Vt) {
    __shared__ bf16_t t[64][72];
    int n0 = blockIdx.x * 64;
    int h = blockIdx.y;
    int tx = threadIdx.x & 63, ty = threadIdx.x >> 6;
#pragma unroll
    for (int i = 0; i < 16; i++) {
        int nl = ty * 16 + i;
        t[nl][tx] = QKV[(size_t)(n0 + nl) * 3072 + 2048 + h * DH + tx];
    }
    __syncthreads();
#pragma unroll
    for (int i = 0; i < 16; i++) {
        int dl = ty * 16 + i;
        Vt[(size_t)(h * DH + dl) * N_TOK + n0 + tx] = t[tx][dl];
    }
}

// ---------------- flash attention, fixed-max softmax, no barriers ----------------
// wave = 32 q-rows of one head; K/V fragments read directly from L2 (hot per-XCD);
// wave pair (rgw, 127-rgw) per block -> uniform block cost (129 tiles), zero tail.
__global__ __launch_bounds__(128) void attn_kernel(const bf16_t* __restrict__ QKV,
                                                   const bf16_t* __restrict__ Vt,
                                                   bf16_t* __restrict__ O) {
    __shared__ __align__(16) bf16_t Pt[2][32 * 40];
    const int tid = threadIdx.x;
    const int wave = tid >> 6;
    const int lane = tid & 63;
    const int l15 = lane & 15;
    const int quad = lane >> 4;

    const int xcd = blockIdx.x & 7;
    const int t = blockIdx.x >> 3;        // 0..127
    const int h = xcd * 2 + (t & 1);      // 2 heads per XCD for K/V L2 residency
    const int u = t >> 1;                 // 0..63
    const int rgw = wave ? u : 127 - u;   // pair heavy+light -> uniform cost
    const int i0 = rgw * 32;
    const int jtw = rgw;                  // last (diagonal) 32-wide j-tile

    const bf16_t* Qb = QKV + h * DH;
    const bf16_t* Kb = QKV + 1024 + h * DH;
    const bf16_t* Vb = Vt + (size_t)h * DH * N_TOK;
    bf16_t* P = Pt[wave];

    bf16x8 aq[2][2];
#pragma unroll
    for (int s_ = 0; s_ < 2; s_++)
#pragma unroll
        for (int kd = 0; kd < 2; kd++)
            aq[s_][kd] = *(const bf16x8*)(Qb + (size_t)(i0 + s_ * 16 + l15) * 3072 +
                                          kd * 32 + quad * 8);

    f32x4 acc[2][4] = {};
    float l_part[2][4] = {};

    bf16x8 bk[2][2], bv[4];
    // preload tile 0 fragments
#pragma unroll
    for (int kd = 0; kd < 2; kd++)
#pragma unroll
        for (int jh = 0; jh < 2; jh++)
            bk[kd][jh] = *(const bf16x8*)(Kb + (size_t)(jh * 16 + l15) * 3072 +
                                          kd * 32 + quad * 8);
#pragma unroll
    for (int ni = 0; ni < 4; ni++)
        bv[ni] = *(const bf16x8*)(Vb + (size_t)(ni * 16 + l15) * N_TOK + quad * 8);

    for (int jt = 0; jt <= jtw; jt++) {
        // ---- QK^T for current tile ----
        f32x4 sS[2][2] = {};
#pragma unroll
        for (int kd = 0; kd < 2; kd++)
#pragma unroll
            for (int s_ = 0; s_ < 2; s_++) {
                sS[s_][0] = __builtin_amdgcn_mfma_f32_16x16x32_bf16(aq[s_][kd], bk[kd][0], sS[s_][0], 0, 0, 0);
                sS[s_][1] = __builtin_amdgcn_mfma_f32_16x16x32_bf16(aq[s_][kd], bk[kd][1], sS[s_][1], 0, 0, 0);
            }
        // prefetch next K fragments (bk consumed above; ~full tile of latency cover)
        if (jt < jtw) {
            const bf16_t* kn = Kb + (size_t)(jt + 1) * 32 * 3072;
#pragma unroll
            for (int kd = 0; kd < 2; kd++)
#pragma unroll
                for (int jh = 0; jh < 2; jh++)
                    bk[kd][jh] = *(const bf16x8*)(kn + (size_t)(jh * 16 + l15) * 3072 +
                                                  kd * 32 + quad * 8);
        }
        // ---- softmax (fixed max: exp2(s*C1 - C2)) + P store ----
        if (jt == jtw) {                  // diagonal tile: causal mask (i0 == j0)
#pragma unroll
            for (int s_ = 0; s_ < 2; s_++)
#pragma unroll
                for (int r = 0; r < 4; r++) {
                    const int il = s_ * 16 + quad * 4 + r;
                    float p0 = (l15 > il) ? 0.f : __builtin_amdgcn_exp2f(sS[s_][0][r] * C1 - C2);
                    float p1 = (16 + l15 > il) ? 0.f : __builtin_amdgcn_exp2f(sS[s_][1][r] * C1 - C2);
                    l_part[s_][r] += p0 + p1;
                    P[il * 40 + l15] = (bf16_t)p0;
                    P[il * 40 + 16 + l15] = (bf16_t)p1;
                }
        } else {
#pragma unroll
            for (int s_ = 0; s_ < 2; s_++)
#pragma unroll
                for (int r = 0; r < 4; r++) {
                    const int il = s_ * 16 + quad * 4 + r;
                    float p0 = __builtin_amdgcn_exp2f(sS[s_][0][r] * C1 - C2);
                    float p1 = __builtin_amdgcn_exp2f(sS[s_][1][r] * C1 - C2);
                    l_part[s_][r] += p0 + p1;
                    P[il * 40 + l15] = (bf16_t)p0;
                    P[il * 40 + 16 + l15] = (bf16_t)p1;
                }
        }
        // ---- P (C-layout) -> A-layout via wave-private LDS; PV ----
#pragma unroll
        for (int s_ = 0; s_ < 2; s_++) {
            bf16x8 ap = *(const bf16x8*)(&P[(s_ * 16 + l15) * 40 + quad * 8]);
#pragma unroll
            for (int ni = 0; ni < 4; ni++)
                acc[s_][ni] = __builtin_amdgcn_mfma_f32_16x16x32_bf16(ap, bv[ni], acc[s_][ni], 0, 0, 0);
        }
        // prefetch next V fragments (covered by next tile's QK+softmax)
        if (jt < jtw) {
            const bf16_t* vn = Vb + (jt + 1) * 32;
#pragma unroll
            for (int ni = 0; ni < 4; ni++)
                bv[ni] = *(const bf16x8*)(vn + (size_t)(ni * 16 + l15) * N_TOK + quad * 8);
        }
    }

    float inv[2][4];
#pragma unroll
    for (int s_ = 0; s_ < 2; s_++)
#pragma unroll
        for (int r = 0; r < 4; r++) {
            float l = l_part[s_][r];
            l += __shfl_xor(l, 1);
            l += __shfl_xor(l, 2);
            l += __shfl_xor(l, 4);
            l += __shfl_xor(l, 8);
            inv[s_][r] = 1.0f / l;
        }
#pragma unroll
    for (int s_ = 0; s_ < 2; s_++)
#pragma unroll
        for (int ni = 0; ni < 4; ni++)
#pragma unroll
            for (int r = 0; r < 4; r++) {
                int i = i0 + s_ * 16 + quad * 4 + r;
                int col = h * DH + ni * 16 + l15;
                O[(size_t)i * D_MODEL + col] = (bf16_t)(acc[s_][ni][r] * inv[s_][r]);
            }
}

extern "C" void kernel_launch(void* const* d_in, const int* in_sizes, int n_in,
                              void* d_out, int out_size, void* d_ws, size_t ws_size,
                              hipStream_t stream) {
    const float* x  = (const float*)d_in[0];
    const float* Wq = (const float*)d_in[1];
    const float* Wk = (const float*)d_in[2];
    const float* Wv = (const float*)d_in[3];
    const float* Wo = (const float*)d_in[4];
    float* out = (float*)d_out;
    char* ws = (char*)d_ws;
    const size_t MB = 1024 * 1024;
    bf16_t* xb   = (bf16_t*)(ws);             // 8 MB
    bf16_t* Wt3  = (bf16_t*)(ws + 8 * MB);    // 6 MB  [3072][1024] q|k|v
    bf16_t* Wot  = (bf16_t*)(ws + 14 * MB);   // 2 MB
    bf16_t* QKV  = (bf16_t*)(ws + 16 * MB);   // 24 MB [4096][3072]
    bf16_t* Vt   = (bf16_t*)(ws + 40 * MB);   // 8 MB  [16][64][4096]
    bf16_t* Ob   = (bf16_t*)(ws + 48 * MB);   // 8 MB  -> ends at 56 MB

    cast_x_kernel<<<4096, 256, 0, stream>>>(x, xb);
    dim3 gw(16, 16, 4);
    transpose_w_kernel<<<gw, 256, 0, stream>>>(Wq, Wk, Wv, Wo,
                                               Wt3, Wt3 + 1024 * 1024, Wt3 + 2 * 1024 * 1024, Wot);
    dim3 gqkv(3072 / 128, N_TOK / 128);
    gemm_tile<0, 1><<<gqkv, 256, 0, stream>>>(xb, Wt3, QKV, 3072);
    dim3 gv(N_TOK / 64, HEADS);
    transpose_v_kernel<<<gv, 256, 0, stream>>>(QKV, Vt);
    attn_kernel<<<1024, 128, 0, stream>>>(QKV, Vt, Ob);
    dim3 go(D_MODEL / 128, N_TOK / 128);
    gemm_tile<1, 0><<<go, 256, 0, stream>>>(Ob, Wot, out, D_MODEL);
}